// Round 1
// baseline (88.763 us; speedup 1.0000x reference)
//
#include <hip/hip_runtime.h>

#define NB 8192
#define ND 128
#define NC 100
#define MARGIN_F 0.3f

__global__ __launch_bounds__(256) void triplet_brdf_kernel(
    const float* __restrict__ inputs,   // (NB, ND) fp32
    const int*   __restrict__ targets,  // (NB,) int32
    const int*   __restrict__ ixs,      // (NB, 2) int32
    const float* __restrict__ brdf,     // (NC, NC) fp32
    float*       __restrict__ out)      // scalar
{
    const int wave = threadIdx.x >> 6;   // 4 waves per block
    const int lane = threadIdx.x & 63;
    const int row  = blockIdx.x * 4 + wave;

    const int i0 = ixs[2 * row];
    const int i1 = ixs[2 * row + 1];

    // Each lane loads float2 -> 64 lanes * 2 = 128 elements = one full row.
    const float2* xr = (const float2*)(inputs + (size_t)row * ND);
    const float2* xa = (const float2*)(inputs + (size_t)i0  * ND);
    const float2* xb = (const float2*)(inputs + (size_t)i1  * ND);

    float2 r = xr[lane];
    float2 a = xa[lane];
    float2 b = xb[lane];

    float dxa = r.x - a.x, dya = r.y - a.y;
    float dxb = r.x - b.x, dyb = r.y - b.y;
    float da = dxa * dxa + dya * dya;
    float db = dxb * dxb + dyb * dyb;

    // wave64 butterfly reduction of both partial sums
    #pragma unroll
    for (int off = 32; off > 0; off >>= 1) {
        da += __shfl_xor(da, off, 64);
        db += __shfl_xor(db, off, 64);
    }

    __shared__ float wsum[4];
    if (lane == 0) {
        // reference: sqrt(clip(d2, 1e-12))
        float d0 = sqrtf(fmaxf(da, 1e-12f));
        float d1 = sqrtf(fmaxf(db, 1e-12f));
        int t  = targets[row];
        int t0 = targets[i0];
        int t1 = targets[i1];
        float md1 = brdf[t * NC + t0];
        float md2 = brdf[t * NC + t1];
        // cond ? (ap=d0, an=d1) : (ap=d1, an=d0)
        float diff = (md1 < md2) ? (d0 - d1) : (d1 - d0);
        wsum[wave] = fmaxf(diff + MARGIN_F, 0.0f);
    }
    __syncthreads();

    if (threadIdx.x == 0) {
        float s = wsum[0] + wsum[1] + wsum[2] + wsum[3];
        atomicAdd(out, s * (1.0f / (float)NB));
    }
}

extern "C" void kernel_launch(void* const* d_in, const int* in_sizes, int n_in,
                              void* d_out, int out_size, void* d_ws, size_t ws_size,
                              hipStream_t stream) {
    const float* inputs  = (const float*)d_in[0];
    const int*   targets = (const int*)d_in[1];
    const int*   ixs     = (const int*)d_in[2];
    const float* brdf    = (const float*)d_in[3];
    float* out = (float*)d_out;

    // d_out is poisoned to 0xAA before every timed launch -> zero it (async, capture-safe)
    hipMemsetAsync(out, 0, sizeof(float), stream);

    triplet_brdf_kernel<<<NB / 4, 256, 0, stream>>>(inputs, targets, ixs, brdf, out);
}

// Round 2
// 66.538 us; speedup vs baseline: 1.3340x; 1.3340x over previous
//
#include <hip/hip_runtime.h>

#define NB 8192
#define ND 128
#define NC 100
#define MARGIN_F 0.3f

#define BLOCKS1 256          // stage-1 blocks
#define WAVES_PB 4           // waves per block (256 threads)
#define ROWS_PER_WAVE 8      // 256*4*8 = 8192 rows

// Stage 1: per-block partial hinge sums -> ws[blockIdx]
__global__ __launch_bounds__(256) void triplet_partial_kernel(
    const float* __restrict__ inputs,   // (NB, ND) fp32
    const int*   __restrict__ targets,  // (NB,) int32
    const int*   __restrict__ ixs,      // (NB, 2) int32
    const float* __restrict__ brdf,     // (NC, NC) fp32
    float*       __restrict__ partial)  // (BLOCKS1,)
{
    const int wave = threadIdx.x >> 6;
    const int lane = threadIdx.x & 63;
    const int wave_id = blockIdx.x * WAVES_PB + wave;   // 0..1023

    float acc = 0.0f;

    #pragma unroll
    for (int it = 0; it < ROWS_PER_WAVE; ++it) {
        const int row = wave_id * ROWS_PER_WAVE + it;

        const int i0 = ixs[2 * row];
        const int i1 = ixs[2 * row + 1];

        // 64 lanes * float2 = 128 floats = one full row, coalesced.
        const float2* xr = (const float2*)(inputs + (size_t)row * ND);
        const float2* xa = (const float2*)(inputs + (size_t)i0  * ND);
        const float2* xb = (const float2*)(inputs + (size_t)i1  * ND);

        float2 r = xr[lane];
        float2 a = xa[lane];
        float2 b = xb[lane];

        float dxa = r.x - a.x, dya = r.y - a.y;
        float dxb = r.x - b.x, dyb = r.y - b.y;
        float da = dxa * dxa + dya * dya;
        float db = dxb * dxb + dyb * dyb;

        // wave64 butterfly: afterwards every lane holds the full sums
        #pragma unroll
        for (int off = 32; off > 0; off >>= 1) {
            da += __shfl_xor(da, off, 64);
            db += __shfl_xor(db, off, 64);
        }

        // uniform across the wave from here on
        float d0 = sqrtf(fmaxf(da, 1e-12f));
        float d1 = sqrtf(fmaxf(db, 1e-12f));
        int t  = targets[row];
        int t0 = targets[i0];
        int t1 = targets[i1];
        float md1 = brdf[t * NC + t0];
        float md2 = brdf[t * NC + t1];
        float diff = (md1 < md2) ? (d0 - d1) : (d1 - d0);
        acc += fmaxf(diff + MARGIN_F, 0.0f);
    }

    __shared__ float wsum[WAVES_PB];
    if (lane == 0) wsum[wave] = acc;
    __syncthreads();
    if (threadIdx.x == 0) {
        float s = 0.0f;
        #pragma unroll
        for (int w = 0; w < WAVES_PB; ++w) s += wsum[w];
        partial[blockIdx.x] = s;
    }
}

// Stage 2: reduce BLOCKS1 partials, overwrite out[0] (no memset needed)
__global__ __launch_bounds__(256) void triplet_reduce_kernel(
    const float* __restrict__ partial,
    float*       __restrict__ out)
{
    const int wave = threadIdx.x >> 6;
    const int lane = threadIdx.x & 63;

    float v = partial[threadIdx.x];   // BLOCKS1 == 256 == blockDim.x

    #pragma unroll
    for (int off = 32; off > 0; off >>= 1)
        v += __shfl_xor(v, off, 64);

    __shared__ float wsum[WAVES_PB];
    if (lane == 0) wsum[wave] = v;
    __syncthreads();
    if (threadIdx.x == 0) {
        float s = 0.0f;
        #pragma unroll
        for (int w = 0; w < WAVES_PB; ++w) s += wsum[w];
        out[0] = s * (1.0f / (float)NB);
    }
}

extern "C" void kernel_launch(void* const* d_in, const int* in_sizes, int n_in,
                              void* d_out, int out_size, void* d_ws, size_t ws_size,
                              hipStream_t stream) {
    const float* inputs  = (const float*)d_in[0];
    const int*   targets = (const int*)d_in[1];
    const int*   ixs     = (const int*)d_in[2];
    const float* brdf    = (const float*)d_in[3];
    float* out     = (float*)d_out;
    float* partial = (float*)d_ws;    // 256 floats of scratch

    triplet_partial_kernel<<<BLOCKS1, 256, 0, stream>>>(inputs, targets, ixs, brdf, partial);
    triplet_reduce_kernel<<<1, 256, 0, stream>>>(partial, out);
}

// Round 3
// 64.251 us; speedup vs baseline: 1.3815x; 1.0356x over previous
//
#include <hip/hip_runtime.h>

#define NB 8192
#define ND 128
#define NC 100
#define MARGIN_F 0.3f

#define BLOCKS1 256          // stage-1 blocks (1 per CU)
#define WAVES_PB 4           // 256 threads = 4 waves
#define ROWS_PER_WAVE 8      // 1024 waves * 8 = 8192 rows
#define ROW_GROUPS 2         // 4 rows handled concurrently per wave -> 2 groups

// Stage 1: 16 lanes per row, 4 rows per wave concurrently.
__global__ __launch_bounds__(256) void triplet_partial_kernel(
    const float* __restrict__ inputs,   // (NB, ND) fp32
    const int*   __restrict__ targets,  // (NB,) int32
    const int*   __restrict__ ixs,      // (NB, 2) int32
    const float* __restrict__ brdf,     // (NC, NC) fp32
    float*       __restrict__ partial)  // (BLOCKS1,)
{
    const int wave = threadIdx.x >> 6;
    const int lane = threadIdx.x & 63;
    const int sub  = lane >> 4;          // which of 4 rows in the group
    const int sl   = lane & 15;          // slot within the row
    const int wave_id = blockIdx.x * WAVES_PB + wave;   // 0..1023

    float acc = 0.0f;

    #pragma unroll
    for (int g = 0; g < ROW_GROUPS; ++g) {
        const int row = wave_id * ROWS_PER_WAVE + g * 4 + sub;

        const int i0 = ixs[2 * row];
        const int i1 = ixs[2 * row + 1];

        // 16 lanes * 2 float4 = 128 floats = full row. 256 B contiguous per
        // 16-lane group -> well coalesced dwordx4 loads.
        const float4* xr = (const float4*)(inputs + (size_t)row * ND);
        const float4* xa = (const float4*)(inputs + (size_t)i0  * ND);
        const float4* xb = (const float4*)(inputs + (size_t)i1  * ND);

        float4 r0 = xr[sl], r1 = xr[sl + 16];
        float4 a0 = xa[sl], a1 = xa[sl + 16];
        float4 b0 = xb[sl], b1 = xb[sl + 16];

        float da, db, t;
        t = r0.x - a0.x; da  = t * t;
        t = r0.y - a0.y; da += t * t;
        t = r0.z - a0.z; da += t * t;
        t = r0.w - a0.w; da += t * t;
        t = r1.x - a1.x; da += t * t;
        t = r1.y - a1.y; da += t * t;
        t = r1.z - a1.z; da += t * t;
        t = r1.w - a1.w; da += t * t;

        t = r0.x - b0.x; db  = t * t;
        t = r0.y - b0.y; db += t * t;
        t = r0.z - b0.z; db += t * t;
        t = r0.w - b0.w; db += t * t;
        t = r1.x - b1.x; db += t * t;
        t = r1.y - b1.y; db += t * t;
        t = r1.z - b1.z; db += t * t;
        t = r1.w - b1.w; db += t * t;

        // 4-step butterfly confined to each 16-lane group (xor of bits 0..3)
        #pragma unroll
        for (int off = 1; off <= 8; off <<= 1) {
            da += __shfl_xor(da, off, 64);
            db += __shfl_xor(db, off, 64);
        }

        if (sl == 0) {   // lanes 0,16,32,48: finish their row
            float d0 = sqrtf(fmaxf(da, 1e-12f));
            float d1 = sqrtf(fmaxf(db, 1e-12f));
            int tt = targets[row];
            int t0 = targets[i0];
            int t1 = targets[i1];
            float md1 = brdf[tt * NC + t0];
            float md2 = brdf[tt * NC + t1];
            float diff = (md1 < md2) ? (d0 - d1) : (d1 - d0);
            acc += fmaxf(diff + MARGIN_F, 0.0f);
        }
    }

    // one full-wave butterfly sums the 8 per-row hinges (acc != 0 only on sl==0 lanes)
    #pragma unroll
    for (int off = 1; off <= 32; off <<= 1)
        acc += __shfl_xor(acc, off, 64);

    __shared__ float wsum[WAVES_PB];
    if (lane == 0) wsum[wave] = acc;
    __syncthreads();
    if (threadIdx.x == 0)
        partial[blockIdx.x] = wsum[0] + wsum[1] + wsum[2] + wsum[3];
}

// Stage 2: one wave reduces 256 partials; overwrites out (no memset needed).
__global__ __launch_bounds__(64) void triplet_reduce_kernel(
    const float* __restrict__ partial,
    float*       __restrict__ out)
{
    float4 v = ((const float4*)partial)[threadIdx.x];   // 64 lanes * 4 = 256
    float s = (v.x + v.y) + (v.z + v.w);
    #pragma unroll
    for (int off = 1; off <= 32; off <<= 1)
        s += __shfl_xor(s, off, 64);
    if (threadIdx.x == 0)
        out[0] = s * (1.0f / (float)NB);
}

extern "C" void kernel_launch(void* const* d_in, const int* in_sizes, int n_in,
                              void* d_out, int out_size, void* d_ws, size_t ws_size,
                              hipStream_t stream) {
    const float* inputs  = (const float*)d_in[0];
    const int*   targets = (const int*)d_in[1];
    const int*   ixs     = (const int*)d_in[2];
    const float* brdf    = (const float*)d_in[3];
    float* out     = (float*)d_out;
    float* partial = (float*)d_ws;    // 256 floats of scratch

    triplet_partial_kernel<<<BLOCKS1, 256, 0, stream>>>(inputs, targets, ixs, brdf, partial);
    triplet_reduce_kernel<<<1, 64, 0, stream>>>(partial, out);
}